// Round 8
// baseline (371.058 us; speedup 1.0000x reference)
//
#include <hip/hip_runtime.h>
#include <float.h>
#include <stdint.h>

constexpr int D_MODEL = 1024;
constexpr int DICT    = 16384;
constexpr int TOPK    = 8;
constexpr int NCAND   = 16;
constexpr int NTOK    = 4096;      // B*T
constexpr int NTILE   = 128;       // DICT / 128
constexpr long long COEFF_COUNT = (long long)NTOK * DICT;

typedef __attribute__((ext_vector_type(8))) __bf16 bf16x8;
typedef __attribute__((ext_vector_type(4))) float  floatx4;

__device__ __forceinline__ unsigned short f2bf(float f) {
    unsigned int u = __float_as_uint(f);
    u = u + 0x7fffu + ((u >> 16) & 1u);     // RNE
    return (unsigned short)(u >> 16);
}

__device__ __forceinline__ void async16(void* lds, const void* g) {
    __builtin_amdgcn_global_load_lds(
        (__attribute__((address_space(1))) void*)g,
        (__attribute__((address_space(3))) void*)lds, 16, 0, 0);
}

// ---------------------------------------------------------------------------
// fused fp32 -> bf16 convert for x and Wenc (one dispatch)
// ---------------------------------------------------------------------------
__global__ __launch_bounds__(256) void ssod_cvt2(const float4* __restrict__ xs, ushort4* __restrict__ xd, int nx4,
                                                 const float4* __restrict__ ws, ushort4* __restrict__ wd, int nw4) {
    const int i = blockIdx.x * 256 + threadIdx.x;
    if (i < nx4) {
        const float4 v = xs[i];
        ushort4 o; o.x = f2bf(v.x); o.y = f2bf(v.y); o.z = f2bf(v.z); o.w = f2bf(v.w);
        xd[i] = o;
    } else {
        const int j = i - nx4;
        if (j < nw4) {
            const float4 v = ws[j];
            ushort4 o; o.x = f2bf(v.x); o.y = f2bf(v.y); o.z = f2bf(v.z); o.w = f2bf(v.w);
            wd[j] = o;
        }
    }
}

// ---------------------------------------------------------------------------
// 256x256-tile, 8-wave bf16 MFMA GEMM — m201-style 8-phase schedule.
// BK=64 per K-tile, 2 LDS buffers x 2 K-halves per operand (128 KiB).
// Per phase: {ds_read frags (4 or 8 b128) | stage one 16KB half (2 gload_lds)
//  -> barrier -> lgkm(0) -> setprio(1) -> 16 MFMA -> setprio(0) -> barrier},
// vmcnt(6) only at phases 4/8 (3 half-tiles in flight). Epilogue as before.
// Ledger: each stage overwrites the region last read one phase earlier; every
// consumed half is >=4 half-stages old at the preceding vmcnt(6).
// ---------------------------------------------------------------------------
#define SGA(buf_, ks_, T_) do {                                              \
    char* d_ = AsW + (buf_) * 32768 + (ks_) * 16384;                         \
    const char* s_ = pA + (T_) * 128 + (ks_) * 64;                           \
    async16(d_, s_); async16(d_ + 8192, s_ + 262144);                        \
} while (0)

#define SGB(buf_, ks_, T_) do {                                              \
    char* d_ = BsW + (buf_) * 32768 + (ks_) * 16384;                         \
    const char* s_ = pB + (T_) * 128 + (ks_) * 64;                           \
    async16(d_, s_); async16(d_ + 8192, s_ + 262144);                        \
} while (0)

#define SGN ((void)0)
#define VM6 asm volatile("s_waitcnt vmcnt(6)" ::: "memory")
#define VM0 asm volatile("s_waitcnt vmcnt(0)" ::: "memory")
#define VMN ((void)0)

// swapped operands: A-op = dict frag (bq), B-op = token frag (af)
#define MR4(m_, AF_)                                                                        \
    acc[m_][0] = __builtin_amdgcn_mfma_f32_16x16x32_bf16(bq0, AF_, acc[m_][0], 0, 0, 0);    \
    acc[m_][1] = __builtin_amdgcn_mfma_f32_16x16x32_bf16(bq1, AF_, acc[m_][1], 0, 0, 0);    \
    acc[m_][2] = __builtin_amdgcn_mfma_f32_16x16x32_bf16(bq2, AF_, acc[m_][2], 0, 0, 0);    \
    acc[m_][3] = __builtin_amdgcn_mfma_f32_16x16x32_bf16(bq3, AF_, acc[m_][3], 0, 0, 0);

#define PH(buf_, ks_, qm_, RB_, STG_, VM_) do {                              \
    const char* ap_ = AsC + (buf_) * 32768 + (ks_) * 16384 + aob + (qm_) * 4096; \
    bf16x8 af0 = *(const bf16x8*)(ap_);                                      \
    bf16x8 af1 = *(const bf16x8*)(ap_ + 1024);                               \
    bf16x8 af2 = *(const bf16x8*)(ap_ + 2048);                               \
    bf16x8 af3 = *(const bf16x8*)(ap_ + 3072);                               \
    if (RB_) {                                                               \
        const char* bp_ = BsC + (buf_) * 32768 + (ks_) * 16384 + bob;        \
        bq0 = *(const bf16x8*)(bp_);                                         \
        bq1 = *(const bf16x8*)(bp_ + 1024);                                  \
        bq2 = *(const bf16x8*)(bp_ + 2048);                                  \
        bq3 = *(const bf16x8*)(bp_ + 3072);                                  \
    }                                                                        \
    STG_;                                                                    \
    asm volatile("s_barrier" ::: "memory");                                  \
    asm volatile("s_waitcnt lgkmcnt(0)" ::: "memory");                       \
    __builtin_amdgcn_s_setprio(1);                                           \
    MR4((qm_) * 4 + 0, af0)                                                  \
    MR4((qm_) * 4 + 1, af1)                                                  \
    MR4((qm_) * 4 + 2, af2)                                                  \
    MR4((qm_) * 4 + 3, af3)                                                  \
    __builtin_amdgcn_s_setprio(0);                                           \
    VM_;                                                                     \
    asm volatile("s_barrier" ::: "memory");                                  \
} while (0)

__global__ __launch_bounds__(512, 2) void ssod_gemm_bf16(const unsigned short* __restrict__ A,
                                                         const unsigned short* __restrict__ B,
                                                         unsigned short* __restrict__ C,
                                                         unsigned short* __restrict__ tmax) {
    __shared__ __align__(16) unsigned short As[2][2][8192];   // [buf][ks][128 rowpairs x 128B]
    __shared__ __align__(16) unsigned short Bs[2][2][8192];

    const int tid  = threadIdx.x;
    const int wave = tid >> 6;
    const int lane = tid & 63;

    // XCD bn-partition: XCD x = bid&7 owns bn in [x*8, x*8+8); bm sweeps slow.
    const int bid = blockIdx.x;
    const int bn  = (bid & 7) * 8 + ((bid >> 3) & 7);
    const int bm  = bid >> 6;

    const int wm = wave >> 2;           // 0..1  (token half, 128 rows)
    const int wn = wave & 3;            // 0..3  (dict quarter, 64 rows)
    const int fr = lane & 15;
    const int kg = lane >> 4;

    // ---- staging source (per-thread, pre-swizzled so LDS dest stays linear) ----
    const int sR   = tid >> 3;                          // rowpair within 16KB half
    const int sinp = ((tid & 7) * 16) ^ ((sR & 7) << 4);
    const int smr  = 2 * sR + (sinp >> 6);              // token/dict row (0..127; +128 via q=1)
    const int skb  = sinp & 63;                         // k byte within 32k half
    const char* pA = (const char*)(A + (size_t)bm * 256 * D_MODEL) + (size_t)smr * 2048 + skb;
    const char* pB = (const char*)(B + (size_t)bn * 256 * D_MODEL) + (size_t)smr * 2048 + skb;

    // ---- ds_read per-thread base offsets (bytes within a 16KB [buf][ks] region) ----
    const int swz = ((((fr & 1) << 6) | (kg << 4)) ^ (((fr >> 1) & 7) << 4));
    const int aob = (wm * 64 + (fr >> 1)) * 128 + swz;
    const int bob = (wn * 32 + (fr >> 1)) * 128 + swz;

    const char* AsC = (const char*)As;
    const char* BsC = (const char*)Bs;
    char* AsW = (char*)As + tid * 16;
    char* BsW = (char*)Bs + tid * 16;

    floatx4 acc[8][4];
    #pragma unroll
    for (int i = 0; i < 8; ++i)
        #pragma unroll
        for (int j = 0; j < 4; ++j) acc[i][j] = floatx4{0.f, 0.f, 0.f, 0.f};

    bf16x8 bq0, bq1, bq2, bq3;

    // ---- prologue: tile0 all 4 halves + 3 halves of tile1; tile0 landed ----
    SGB(0, 0, 0); SGA(0, 0, 0); SGB(0, 1, 0); SGA(0, 1, 0);
    SGB(1, 0, 1); SGA(1, 0, 1); SGB(1, 1, 1);
    asm volatile("s_waitcnt vmcnt(6)" ::: "memory");
    asm volatile("s_barrier" ::: "memory");

    // ---- main loop: 16 K-tiles of 64, 2 per iteration, 8 phases each ----
    #pragma unroll 1
    for (int i = 0; i < 7; ++i) {
        const int t1 = 2 * i + 1, t2 = 2 * i + 2, t3 = 2 * i + 3;
        PH(0, 0, 0, 1, SGA(1, 1, t1), VMN);
        PH(0, 0, 1, 0, SGB(0, 0, t2), VMN);
        PH(0, 1, 0, 1, SGA(0, 0, t2), VMN);
        PH(0, 1, 1, 0, SGB(0, 1, t2), VM6);
        PH(1, 0, 0, 1, SGA(0, 1, t2), VMN);
        PH(1, 0, 1, 0, SGB(1, 0, t3), VMN);
        PH(1, 1, 0, 1, SGA(1, 0, t3), VMN);
        PH(1, 1, 1, 0, SGB(1, 1, t3), VM6);
    }
    // last iteration (tiles 14,15): stage only Ak1(15); drain at ph4
    PH(0, 0, 0, 1, SGA(1, 1, 15), VMN);
    PH(0, 0, 1, 0, SGN, VMN);
    PH(0, 1, 0, 1, SGN, VMN);
    PH(0, 1, 1, 0, SGN, VM0);
    PH(1, 0, 0, 1, SGN, VMN);
    PH(1, 0, 1, 0, SGN, VMN);
    PH(1, 1, 0, 1, SGN, VMN);
    PH(1, 1, 1, 0, SGN, VMN);

    // ---- epilogue: packed dwordx2 C-write + per-128-col tile-max ----
    __syncthreads();
    unsigned int* rmax = (unsigned int*)&As[0][0][0];  // 512 entries: [token][half]
    rmax[tid] = 0;
    __syncthreads();

    const int tcol  = lane & 15;                       // token offset in frag
    const int rq4   = (lane >> 4) * 4;                 // dict quad base
    const int half  = wn >> 1;                         // 128-col tile within block
    const int dbase = bn * 256 + wn * 64 + rq4;

    #pragma unroll
    for (int mf = 0; mf < 8; ++mf) {
        const int tok = wm * 128 + mf * 16 + tcol;     // block-local token
        unsigned int tm = 0;
        #pragma unroll
        for (int nf = 0; nf < 4; ++nf) {
            const floatx4 a = acc[mf][nf];
            const unsigned int b0 = f2bf(a[0]), b1 = f2bf(a[1]);
            const unsigned int b2 = f2bf(a[2]), b3 = f2bf(a[3]);
            tm = max(tm, max(max(b0 ^ 0x8000u, b1 ^ 0x8000u),
                             max(b2 ^ 0x8000u, b3 ^ 0x8000u)));
            uint2 pk; pk.x = b0 | (b1 << 16); pk.y = b2 | (b3 << 16);
            *(uint2*)(C + (size_t)(bm * 256 + tok) * DICT + dbase + nf * 16) = pk;
        }
        tm = max(tm, (unsigned int)__shfl_xor((int)tm, 16, 64));
        tm = max(tm, (unsigned int)__shfl_xor((int)tm, 32, 64));
        if (lane < 16) atomicMax(&rmax[tok * 2 + half], tm);
    }
    __syncthreads();
    tmax[(size_t)(bm * 256 + (tid >> 1)) * NTILE + bn * 2 + (tid & 1)] =
        (unsigned short)rmax[tid];
}

#undef PH
#undef MR4
#undef SGA
#undef SGB
#undef SGN
#undef VM6
#undef VM0
#undef VMN

// ---------------------------------------------------------------------------
// Fused select + refine + offset. One block (256 thr) per token.
// ---------------------------------------------------------------------------
__device__ __forceinline__ bool tk_better(float v1, int i1, float v2, int i2) {
    return (v1 > v2) || (v1 == v2 && i1 < i2);
}

__global__ __launch_bounds__(256) void ssod_select_refine(const unsigned short* __restrict__ coeffs,
                                                          const unsigned short* __restrict__ tmax,
                                                          const float* __restrict__ x,
                                                          const float* __restrict__ Wenc,
                                                          const float* __restrict__ Wdict,
                                                          float* __restrict__ outp,
                                                          float* __restrict__ tsum,
                                                          int tokBase) {
    const int tl   = blockIdx.x;          // chunk-local token
    const int t    = tokBase + tl;        // global token
    const int tid  = threadIdx.x;
    const int lane = tid & 63;
    const int wave = tid >> 6;

    __shared__ unsigned int keys[128];
    __shared__ int   tlist[64];
    __shared__ int   ncnt, kcnt;
    __shared__ unsigned int sTau;
    __shared__ float xs[D_MODEL];
    __shared__ int   cidx[NCAND];
    __shared__ float cval[NCAND];
    __shared__ float sval[TOPK];
    __shared__ int   sidx[TOPK];

    // stage x into LDS (used in phase B)
    ((float4*)xs)[tid] = ((const float4*)(x + (size_t)t * D_MODEL))[tid];
    if (tid == 0) { ncnt = 0; kcnt = 0; }
    __syncthreads();

    // ---- tau: 16th-largest of the 128 tile maxes (wave 0, 2-reg bitonic) ----
    const unsigned short* tmrow = tmax + (size_t)t * NTILE;
    if (wave == 0) {
        const unsigned int u = ((const unsigned int*)tmrow)[lane];
        unsigned int v0 = u & 0xFFFFu, v1 = u >> 16;
        for (int k = 2; k <= 128; k <<= 1) {
            for (int j = k >> 1; j >= 1; j >>= 1) {
                if (j == 64) {
                    const unsigned int a = max(v0, v1), b = min(v0, v1);
                    v0 = a; v1 = b;
                } else {
                    const unsigned int p0 = __shfl_xor(v0, j, 64);
                    const unsigned int p1 = __shfl_xor(v1, j, 64);
                    const bool tm0 = ((lane & j) == 0) ^ ((( lane      ) & k) != 0);
                    const bool tm1 = ((lane & j) == 0) ^ (((lane + 64) & k) != 0);
                    v0 = tm0 ? max(v0, p0) : min(v0, p0);
                    v1 = tm1 ? max(v1, p1) : min(v1, p1);
                }
            }
        }
        if (lane == 15) sTau = v0;       // descending: lane 15 = 16th largest
    }
    __syncthreads();
    const unsigned int tau = sTau;

    // ---- qualifying tile list (max >= tau): >=16 tiles by construction ----
    if (tid < NTILE) {
        if ((unsigned int)tmrow[tid] >= tau) {
            const int p = atomicAdd(&ncnt, 1);
            if (p < 64) tlist[p] = tid;
        }
    }
    __syncthreads();
    const int nq = min(ncnt, 64);

    // ---- collect elems >= tau from qualifying tiles ----
    const uint4* row4 = (const uint4*)(coeffs + (size_t)tl * DICT);
    for (int j = tid; j < nq * 16; j += 256) {
        const int tile = tlist[j >> 4];
        const int sub  = j & 15;
        const uint4 p = row4[tile * 16 + sub];
        unsigned int w[4] = {p.x ^ 0x80008000u, p.y ^ 0x80008000u,
                             p.z ^ 0x80008000u, p.w ^ 0x80008000u};
        const int base = tile * 128 + sub * 8;
        #pragma unroll
        for (int h = 0; h < 4; ++h) {
            const unsigned int lo = w[h] & 0xFFFFu, hi = w[h] >> 16;
            if (lo >= tau) {
                const int q = atomicAdd(&kcnt, 1);
                if (q < 128) keys[q] = (lo << 16) | (unsigned)(16383 - (base + h * 2));
            }
            if (hi >= tau) {
                const int q = atomicAdd(&kcnt, 1);
                if (q < 128) keys[q] = (hi << 16) | (unsigned)(16383 - (base + h * 2 + 1));
            }
        }
    }
    __syncthreads();
    const int m = min(kcnt, 128);
    for (int i = m + tid; i < 128; i += 256) keys[i] = 0;
    __syncthreads();

    // ---- wave 0: bitonic sort 128 keys desc, emit top-16 indices ----
    if (wave == 0) {
        unsigned int v0 = keys[lane], v1 = keys[lane + 64];
        for (int k = 2; k <= 128; k <<= 1) {
            for (int j = k >> 1; j >= 1; j >>= 1) {
                if (j == 64) {
                    const unsigned int a = max(v0, v1), b = min(v0, v1);
                    v0 = a; v1 = b;
                } else {
                    const unsigned int p0 = __shfl_xor(v0, j, 64);
                    const unsigned int p1 = __shfl_xor(v1, j, 64);
                    const bool tm0 = ((lane & j) == 0) ^ ((( lane      ) & k) != 0);
                    const bool tm1 = ((lane & j) == 0) ^ (((lane + 64) & k) != 0);
                    v0 = tm0 ? max(v0, p0) : min(v0, p0);
                    v1 = tm1 ? max(v1, p1) : min(v1, p1);
                }
            }
        }
        if (lane < NCAND) cidx[lane] = 16383 - (int)(v0 & 0xFFFFu);
    }
    __syncthreads();

    // ---- Phase B: fp32 refine of 16 candidates (4 per wave, loads up front) ----
    const float4* xs4 = (const float4*)xs;
    float4 xv[4];
    #pragma unroll
    for (int q = 0; q < 4; ++q) xv[q] = xs4[q * 64 + lane];

    float4 wv[4][4];
    #pragma unroll
    for (int s = 0; s < 4; ++s) {
        const float4* wr4 = (const float4*)(Wenc + (size_t)cidx[s * 4 + wave] * D_MODEL);
        #pragma unroll
        for (int q = 0; q < 4; ++q) wv[s][q] = wr4[q * 64 + lane];
    }
    #pragma unroll
    for (int s = 0; s < 4; ++s) {
        float sum = 0.f;
        #pragma unroll
        for (int q = 0; q < 4; ++q)
            sum += xv[q].x * wv[s][q].x + xv[q].y * wv[s][q].y +
                   xv[q].z * wv[s][q].z + xv[q].w * wv[s][q].w;
        #pragma unroll
        for (int off = 32; off > 0; off >>= 1) sum += __shfl_down(sum, off, 64);
        if (lane == 0) cval[s * 4 + wave] = sum;
    }
    __syncthreads();

    // ---- parallel rank-based exact top-8 ----
    if (tid < NCAND) {
        const float v = cval[tid];
        const int  ix = cidx[tid];
        int rank = 0;
        #pragma unroll
        for (int j = 0; j < NCAND; ++j)
            rank += (j != tid) && tk_better(cval[j], cidx[j], v, ix);
        if (rank < TOPK) { sval[rank] = v; sidx[rank] = ix; }
    }
    __syncthreads();
    if (tid == 0) {
        float s = 0.f;
        #pragma unroll
        for (int k = 0; k < TOPK; ++k) s += fabsf(sval[k]);
        tsum[t] = s;
    }

    // ---- offset ----
    const int dd = tid * 4;
    float4 a = make_float4(0.f, 0.f, 0.f, 0.f);
    #pragma unroll
    for (int k = 0; k < TOPK; ++k) {
        const float4 r = *(const float4*)(Wdict + (size_t)sidx[k] * D_MODEL + dd);
        const float s = sval[k];
        a.x += s * r.x; a.y += s * r.y; a.z += s * r.z; a.w += s * r.w;
    }
    *(float4*)(outp + (size_t)t * D_MODEL + dd) = a;
}

// ---------------------------------------------------------------------------
// loss = sum(tsum) / (NTOK*DICT)
// ---------------------------------------------------------------------------
__global__ __launch_bounds__(256) void ssod_loss(const float* __restrict__ tsum,
                                                 float* __restrict__ out) {
    float s = 0.f;
    for (int i = threadIdx.x; i < NTOK; i += 256) s += tsum[i];
    #pragma unroll
    for (int off = 32; off > 0; off >>= 1) s += __shfl_down(s, off, 64);
    __shared__ float wsum[4];
    if ((threadIdx.x & 63) == 0) wsum[threadIdx.x >> 6] = s;
    __syncthreads();
    if (threadIdx.x == 0) {
        const float tot = wsum[0] + wsum[1] + wsum[2] + wsum[3];
        out[(size_t)NTOK * D_MODEL] = tot / (float)COEFF_COUNT;
    }
}

// ---------------------------------------------------------------------------
extern "C" void kernel_launch(void* const* d_in, const int* in_sizes, int n_in,
                              void* d_out, int out_size, void* d_ws, size_t ws_size,
                              hipStream_t stream) {
    const float* x     = (const float*)d_in[0];   // [4096,1024]
    const float* Wenc  = (const float*)d_in[1];   // [16384,1024]
    const float* Wdict = (const float*)d_in[2];   // [16384,1024]
    float* out = (float*)d_out;

    char* ws = (char*)d_ws;
    size_t off = 0;
    unsigned short* xbf  = (unsigned short*)(ws + off); off += (size_t)NTOK * D_MODEL * 2;  // 8 MB
    unsigned short* wbf  = (unsigned short*)(ws + off); off += (size_t)DICT * D_MODEL * 2;  // 33.6 MB
    unsigned short* tmax = (unsigned short*)(ws + off); off += (size_t)NTOK * NTILE * 2;    // 1 MB
    float* tsum = (float*)(ws + off);                   off += (size_t)NTOK * 4;            // 16 KB
    unsigned short* coeffs = (unsigned short*)(ws + off);

    // largest token chunk whose bf16 coeff buffer fits remaining ws
    const size_t remain = (ws_size > off) ? (ws_size - off) : 0;
    int chunk = 512;
    if (remain >= (size_t)4096 * DICT * 2) chunk = 4096;
    else if (remain >= (size_t)2048 * DICT * 2) chunk = 2048;
    else if (remain >= (size_t)1024 * DICT * 2) chunk = 1024;

    const int nx4 = NTOK * D_MODEL / 4;
    const int nw4 = DICT * D_MODEL / 4;
    ssod_cvt2<<<(nx4 + nw4 + 255) / 256, 256, 0, stream>>>(
        (const float4*)x, (ushort4*)xbf, nx4, (const float4*)Wenc, (ushort4*)wbf, nw4);

    for (int tokBase = 0; tokBase < NTOK; tokBase += chunk) {
        const int mtiles = chunk / 256;
        ssod_gemm_bf16<<<mtiles * 64, 512, 0, stream>>>(xbf + (size_t)tokBase * D_MODEL, wbf, coeffs,
                                                        tmax + (size_t)tokBase * NTILE);
        ssod_select_refine<<<chunk, 256, 0, stream>>>(coeffs, tmax, x, Wenc, Wdict, out, tsum, tokBase);
    }
    ssod_loss<<<1, 256, 0, stream>>>(tsum, out);
}

// Round 9
// 370.527 us; speedup vs baseline: 1.0014x; 1.0014x over previous
//
#include <hip/hip_runtime.h>
#include <float.h>
#include <stdint.h>

constexpr int D_MODEL = 1024;
constexpr int DICT    = 16384;
constexpr int TOPK    = 8;
constexpr int NCAND   = 16;
constexpr int NTOK    = 4096;      // B*T
constexpr int NTILE   = 128;       // DICT / 128
constexpr long long COEFF_COUNT = (long long)NTOK * DICT;

typedef __attribute__((ext_vector_type(8))) __bf16 bf16x8;
typedef __attribute__((ext_vector_type(4))) float  floatx4;

__device__ __forceinline__ unsigned short f2bf(float f) {
    unsigned int u = __float_as_uint(f);
    u = u + 0x7fffu + ((u >> 16) & 1u);     // RNE
    return (unsigned short)(u >> 16);
}

__device__ __forceinline__ void async16(void* lds, const void* g) {
    __builtin_amdgcn_global_load_lds(
        (__attribute__((address_space(1))) void*)g,
        (__attribute__((address_space(3))) void*)lds, 16, 0, 0);
}

// ---------------------------------------------------------------------------
// fused fp32 -> bf16 convert for x and Wenc (one dispatch)
// ---------------------------------------------------------------------------
__global__ __launch_bounds__(256) void ssod_cvt2(const float4* __restrict__ xs, ushort4* __restrict__ xd, int nx4,
                                                 const float4* __restrict__ ws, ushort4* __restrict__ wd, int nw4) {
    const int i = blockIdx.x * 256 + threadIdx.x;
    if (i < nx4) {
        const float4 v = xs[i];
        ushort4 o; o.x = f2bf(v.x); o.y = f2bf(v.y); o.z = f2bf(v.z); o.w = f2bf(v.w);
        xd[i] = o;
    } else {
        const int j = i - nx4;
        if (j < nw4) {
            const float4 v = ws[j];
            ushort4 o; o.x = f2bf(v.x); o.y = f2bf(v.y); o.z = f2bf(v.z); o.w = f2bf(v.w);
            wd[j] = o;
        }
    }
}

// ---------------------------------------------------------------------------
// 256x256-tile, 8-wave bf16 MFMA GEMM. ONE barrier per K-tile; frag regs
// double-buffered (RA/RB); ds_reads for tile T+1 issue right after the
// barrier so the LDS burst overlaps the 32-MFMA cluster. Counted vmcnt
// (8 steady / 4 / 0 tail). Swapped MFMA operands -> D[dict][token]:
// packed dwordx2 C-stores. XCD bn-partition for L2 locality.
// (Proven plateau: 159 us. 8-phase port regressed to 180 — reverted.)
// ---------------------------------------------------------------------------
constexpr size_t R1OFF = (size_t)128 * (D_MODEL * 2);   // +128 rows in global

#define STAGE_A(buf_, t_) do {                                               \
    const char* s_ = pA + (size_t)(t_) * 64;                                 \
    char* d_ = (char*)&As[(buf_)][0] + wave * 1024;                          \
    async16(d_, s_); async16(d_ + 8192, s_ + R1OFF);                         \
} while (0)

#define STAGE_B(buf_, t_) do {                                               \
    const char* s_ = pB + (size_t)(t_) * 64;                                 \
    char* d_ = (char*)&Bs[(buf_)][0] + wave * 1024;                          \
    async16(d_, s_); async16(d_ + 8192, s_ + R1OFF);                         \
} while (0)

#define LOADFRAGS(P, buf_) do {                                              \
    const char* ab_ = (const char*)As + (buf_) * 16384 + aob;                \
    const char* bb_ = (const char*)Bs + (buf_) * 16384 + bob;                \
    P##af0 = *(const bf16x8*)(ab_);                                          \
    P##af1 = *(const bf16x8*)(ab_ + 1024);                                   \
    P##af2 = *(const bf16x8*)(ab_ + 2048);                                   \
    P##af3 = *(const bf16x8*)(ab_ + 3072);                                   \
    P##af4 = *(const bf16x8*)(ab_ + 4096);                                   \
    P##af5 = *(const bf16x8*)(ab_ + 5120);                                   \
    P##af6 = *(const bf16x8*)(ab_ + 6144);                                   \
    P##af7 = *(const bf16x8*)(ab_ + 7168);                                   \
    P##bq0 = *(const bf16x8*)(bb_);                                          \
    P##bq1 = *(const bf16x8*)(bb_ + 1024);                                   \
    P##bq2 = *(const bf16x8*)(bb_ + 2048);                                   \
    P##bq3 = *(const bf16x8*)(bb_ + 3072);                                   \
} while (0)

// swapped operands: A-op = dict frag (bq), B-op = token frag (af)
// -> D row = dict offset (regs), D col = token offset (lane&15)
#define MROW(P, AF, m_)                                                                     \
    acc[m_][0] = __builtin_amdgcn_mfma_f32_16x16x32_bf16(P##bq0, AF, acc[m_][0], 0, 0, 0);  \
    acc[m_][1] = __builtin_amdgcn_mfma_f32_16x16x32_bf16(P##bq1, AF, acc[m_][1], 0, 0, 0);  \
    acc[m_][2] = __builtin_amdgcn_mfma_f32_16x16x32_bf16(P##bq2, AF, acc[m_][2], 0, 0, 0);  \
    acc[m_][3] = __builtin_amdgcn_mfma_f32_16x16x32_bf16(P##bq3, AF, acc[m_][3], 0, 0, 0);

#define C1(P) MROW(P, P##af0, 0) MROW(P, P##af1, 1) MROW(P, P##af2, 2) MROW(P, P##af3, 3)
#define C2(P) MROW(P, P##af4, 4) MROW(P, P##af5, 5) MROW(P, P##af6, 6) MROW(P, P##af7, 7)

#define TILE(T_, CONS, LOAD, DOSTAGE, VMI) do {                              \
    if (DOSTAGE) {                                                           \
        STAGE_A(((T_) + 3) & 3, (T_) + 3);                                   \
        STAGE_B(((T_) + 3) & 3, (T_) + 3);                                   \
    }                                                                        \
    asm volatile("s_waitcnt vmcnt(" #VMI ")" ::: "memory");                  \
    asm volatile("s_barrier" ::: "memory");                                  \
    LOADFRAGS(LOAD, ((T_) + 1) & 3);                                         \
    __builtin_amdgcn_s_setprio(1);                                           \
    C1(CONS)                                                                 \
    C2(CONS)                                                                 \
    __builtin_amdgcn_s_setprio(0);                                           \
} while (0)

__global__ __launch_bounds__(512, 2) void ssod_gemm_bf16(const unsigned short* __restrict__ A,
                                                         const unsigned short* __restrict__ B,
                                                         unsigned short* __restrict__ C,
                                                         unsigned short* __restrict__ tmax) {
    __shared__ __align__(16) unsigned short As[4][8192];   // 4 ring slots x 16KB
    __shared__ __align__(16) unsigned short Bs[4][8192];

    const int tid  = threadIdx.x;
    const int wave = tid >> 6;
    const int lane = tid & 63;

    // XCD bn-partition: XCD x = bid&7 owns bn in [x*8, x*8+8); bm sweeps slow.
    const int bid = blockIdx.x;
    const int bn  = (bid & 7) * 8 + ((bid >> 3) & 7);
    const int bm  = bid >> 6;

    const int wm = wave >> 2;           // 0..1  (token half, 128 rows)
    const int wn = wave & 3;            // 0..3  (dict quarter, 64 cols)
    const int fr = lane & 15;
    const int kg = lane >> 4;

    // ---- staging source (per-thread, pre-swizzled so LDS dest stays linear) ----
    const int sR   = tid >> 3;                          // LDS row within round
    const int sinp = ((tid & 7) * 16) ^ ((sR & 7) << 4);
    const int smr  = 2 * sR + (sinp >> 6);              // M-row within round
    const int skb  = sinp & 63;                         // k byte
    const char* pA = (const char*)(A + (size_t)bm * 256 * D_MODEL) + (size_t)smr * (D_MODEL * 2) + skb;
    const char* pB = (const char*)(B + (size_t)bn * 256 * D_MODEL) + (size_t)smr * (D_MODEL * 2) + skb;

    // ---- ds_read per-thread base offsets (bytes) ----
    const int swz = ((((fr & 1) << 6) | (kg << 4)) ^ (((fr >> 1) & 7) << 4));
    const int aob = (wm * 64 + (fr >> 1)) * 128 + swz;
    const int bob = (wn * 32 + (fr >> 1)) * 128 + swz;

    floatx4 acc[8][4];
    #pragma unroll
    for (int i = 0; i < 8; ++i)
        #pragma unroll
        for (int j = 0; j < 4; ++j) acc[i][j] = floatx4{0.f, 0.f, 0.f, 0.f};

    bf16x8 RA_af0, RA_af1, RA_af2, RA_af3, RA_af4, RA_af5, RA_af6, RA_af7;
    bf16x8 RA_bq0, RA_bq1, RA_bq2, RA_bq3;
    bf16x8 RB_af0, RB_af1, RB_af2, RB_af3, RB_af4, RB_af5, RB_af6, RB_af7;
    bf16x8 RB_bq0, RB_bq1, RB_bq2, RB_bq3;

    // ---- prologue: stage tiles 0..2 (12 loads), publish slot 0, preload frags
    STAGE_A(0, 0); STAGE_B(0, 0);
    STAGE_A(1, 1); STAGE_B(1, 1);
    STAGE_A(2, 2); STAGE_B(2, 2);
    asm volatile("s_waitcnt vmcnt(8)" ::: "memory");
    asm volatile("s_barrier" ::: "memory");
    LOADFRAGS(RA_, 0);

    // ---- main loop: 32 K-tiles of 32; one barrier per tile ----
    #pragma unroll 1
    for (int T = 0; T < 28; T += 2) {
        TILE(T,     RA_, RB_, true, 8);
        TILE(T + 1, RB_, RA_, true, 8);
    }
    TILE(28, RA_, RB_, true,  8);
    TILE(29, RB_, RA_, false, 4);
    TILE(30, RA_, RB_, false, 0);
    __builtin_amdgcn_s_setprio(1);
    C1(RB_)
    C2(RB_)
    __builtin_amdgcn_s_setprio(0);

    // ---- epilogue: packed dwordx2 C-write + per-128-col tile-max ----
    __syncthreads();
    unsigned int* rmax = (unsigned int*)&As[0][0];     // 512 entries: [token][half]
    rmax[tid] = 0;
    __syncthreads();

    const int tcol  = lane & 15;                       // token offset in frag
    const int rq4   = (lane >> 4) * 4;                 // dict quad base
    const int half  = wn >> 1;                         // 128-col tile within block
    const int dbase = bn * 256 + wn * 64 + rq4;

    #pragma unroll
    for (int mf = 0; mf < 8; ++mf) {
        const int tok = wm * 128 + mf * 16 + tcol;     // block-local token
        unsigned int tm = 0;
        #pragma unroll
        for (int nf = 0; nf < 4; ++nf) {
            const floatx4 a = acc[mf][nf];
            const unsigned int b0 = f2bf(a[0]), b1 = f2bf(a[1]);
            const unsigned int b2 = f2bf(a[2]), b3 = f2bf(a[3]);
            tm = max(tm, max(max(b0 ^ 0x8000u, b1 ^ 0x8000u),
                             max(b2 ^ 0x8000u, b3 ^ 0x8000u)));
            uint2 pk; pk.x = b0 | (b1 << 16); pk.y = b2 | (b3 << 16);
            *(uint2*)(C + (size_t)(bm * 256 + tok) * DICT + dbase + nf * 16) = pk;
        }
        tm = max(tm, (unsigned int)__shfl_xor((int)tm, 16, 64));
        tm = max(tm, (unsigned int)__shfl_xor((int)tm, 32, 64));
        if (lane < 16) atomicMax(&rmax[tok * 2 + half], tm);
    }
    __syncthreads();
    tmax[(size_t)(bm * 256 + (tid >> 1)) * NTILE + bn * 2 + (tid & 1)] =
        (unsigned short)rmax[tid];
}

#undef TILE
#undef C1
#undef C2
#undef MROW
#undef LOADFRAGS
#undef STAGE_A
#undef STAGE_B

// ---------------------------------------------------------------------------
// Fused select + refine + offset — ONE WAVE PER TOKEN (4 tokens/block).
// No __syncthreads: all phases wave-private (intra-wave LDS is in-order).
// Same tau / key-set / sort / fp32-refine math as the proven block version;
// only fp32 summation order differs (err ~1e-6 << 0.016 rank gap).
// ---------------------------------------------------------------------------
__device__ __forceinline__ bool tk_better(float v1, int i1, float v2, int i2) {
    return (v1 > v2) || (v1 == v2 && i1 < i2);
}

__device__ __forceinline__ int lane_prefix(unsigned long long m) {
    return __builtin_amdgcn_mbcnt_hi((unsigned)(m >> 32),
           __builtin_amdgcn_mbcnt_lo((unsigned)m, 0));
}

__global__ __launch_bounds__(256) void ssod_select_refine(const unsigned short* __restrict__ coeffs,
                                                          const unsigned short* __restrict__ tmax,
                                                          const float* __restrict__ x,
                                                          const float* __restrict__ Wenc,
                                                          const float* __restrict__ Wdict,
                                                          float* __restrict__ outp,
                                                          float* __restrict__ tsum,
                                                          int tokBase) {
    const int tid  = threadIdx.x;
    const int wave = tid >> 6;
    const int lane = tid & 63;
    const int tl   = blockIdx.x * 4 + wave;   // chunk-local token
    const int t    = tokBase + tl;            // global token

    __shared__ unsigned int keys[4][128];
    __shared__ int   tlist[4][64];
    __shared__ int   kcnt[4];
    __shared__ float cval[4][NCAND];
    __shared__ int   cidxs[4][NCAND];
    __shared__ float sval[4][TOPK];
    __shared__ int   sidx[4][TOPK];

    if (lane == 0) kcnt[wave] = 0;

    // ---- tau: 16th-largest of the 128 tile maxes (2-reg wave bitonic) ----
    const unsigned short* tmrow = tmax + (size_t)t * NTILE;
    const unsigned int u = ((const unsigned int*)tmrow)[lane];
    unsigned int v0 = u & 0xFFFFu, v1 = u >> 16;
    for (int k = 2; k <= 128; k <<= 1) {
        for (int j = k >> 1; j >= 1; j >>= 1) {
            if (j == 64) {
                const unsigned int a = max(v0, v1), b = min(v0, v1);
                v0 = a; v1 = b;
            } else {
                const unsigned int p0 = __shfl_xor(v0, j, 64);
                const unsigned int p1 = __shfl_xor(v1, j, 64);
                const bool tm0 = ((lane & j) == 0) ^ ((( lane      ) & k) != 0);
                const bool tm1 = ((lane & j) == 0) ^ (((lane + 64) & k) != 0);
                v0 = tm0 ? max(v0, p0) : min(v0, p0);
                v1 = tm1 ? max(v1, p1) : min(v1, p1);
            }
        }
    }
    const unsigned int tau = (unsigned int)__shfl((int)v0, 15, 64);

    // ---- qualifying tiles: lane covers tiles 2*lane, 2*lane+1 (ballot/prefix) ----
    {
        const unsigned int lo = u & 0xFFFFu, hi = u >> 16;
        const unsigned long long b0 = __ballot(lo >= tau);
        const unsigned long long b1 = __ballot(hi >= tau);
        const int base1 = __popcll(b0);
        if (lo >= tau) { const int p = lane_prefix(b0);         if (p < 64) tlist[wave][p] = 2 * lane; }
        if (hi >= tau) { const int p = base1 + lane_prefix(b1); if (p < 64) tlist[wave][p] = 2 * lane + 1; }
        const int nqf = min(base1 + __popcll(b1), 64);

        // ---- collect elems >= tau from qualifying tiles ----
        const uint4* row4 = (const uint4*)(coeffs + (size_t)tl * DICT);
        for (int j = lane; j < nqf * 16; j += 64) {
            const int tile = tlist[wave][j >> 4];
            const int sub  = j & 15;
            const uint4 p = row4[tile * 16 + sub];
            unsigned int w[4] = {p.x ^ 0x80008000u, p.y ^ 0x80008000u,
                                 p.z ^ 0x80008000u, p.w ^ 0x80008000u};
            const int base = tile * 128 + sub * 8;
            #pragma unroll
            for (int h = 0; h < 4; ++h) {
                const unsigned int lo2 = w[h] & 0xFFFFu, hi2 = w[h] >> 16;
                if (lo2 >= tau) {
                    const int q = atomicAdd(&kcnt[wave], 1);
                    if (q < 128) keys[wave][q] = (lo2 << 16) | (unsigned)(16383 - (base + h * 2));
                }
                if (hi2 >= tau) {
                    const int q = atomicAdd(&kcnt[wave], 1);
                    if (q < 128) keys[wave][q] = (hi2 << 16) | (unsigned)(16383 - (base + h * 2 + 1));
                }
            }
        }
    }
    {
        const int m = min(kcnt[wave], 128);
        for (int i = m + lane; i < 128; i += 64) keys[wave][i] = 0;
    }

    // ---- wave bitonic sort 128 keys desc, top-16 candidates ----
    v0 = keys[wave][lane]; v1 = keys[wave][lane + 64];
    for (int k = 2; k <= 128; k <<= 1) {
        for (int j = k >> 1; j >= 1; j >>= 1) {
            if (j == 64) {
                const unsigned int a = max(v0, v1), b = min(v0, v1);
                v0 = a; v1 = b;
            } else {
                const unsigned int p0 = __shfl_xor(v0, j, 64);
                const unsigned int p1 = __shfl_xor(v1, j, 64);
                const bool tm0 = ((lane & j) == 0) ^ ((( lane      ) & k) != 0);
                const bool tm1 = ((lane & j) == 0) ^ (((lane + 64) & k) != 0);
                v0 = tm0 ? max(v0, p0) : min(v0, p0);
                v1 = tm1 ? max(v1, p1) : min(v1, p1);
            }
        }
    }
    const int my_cidx = 16383 - (int)(v0 & 0xFFFFu);   // valid on lanes 0..15
    if (lane < NCAND) cidxs[wave][lane] = my_cidx;

    // ---- fp32 refine: 4 passes x 4 candidates ----
    const float4* xr = (const float4*)(x + (size_t)t * D_MODEL);
    const float4 xv0 = xr[lane], xv1 = xr[lane + 64], xv2 = xr[lane + 128], xv3 = xr[lane + 192];

    #pragma unroll
    for (int p = 0; p < 4; ++p) {
        const int c0 = __shfl(my_cidx, 4 * p + 0, 64);
        const int c1 = __shfl(my_cidx, 4 * p + 1, 64);
        const int c2 = __shfl(my_cidx, 4 * p + 2, 64);
        const int c3 = __shfl(my_cidx, 4 * p + 3, 64);
        const float4* w0 = (const float4*)(Wenc + (size_t)c0 * D_MODEL);
        const float4* w1 = (const float4*)(Wenc + (size_t)c1 * D_MODEL);
        const float4* w2 = (const float4*)(Wenc + (size_t)c2 * D_MODEL);
        const float4* w3 = (const float4*)(Wenc + (size_t)c3 * D_MODEL);
        float s0 = 0.f, s1 = 0.f, s2 = 0.f, s3 = 0.f;
        #pragma unroll
        for (int j = 0; j < 4; ++j) {
            const float4 xj = (j == 0) ? xv0 : (j == 1) ? xv1 : (j == 2) ? xv2 : xv3;
            const int ix = lane + 64 * j;
            const float4 a0 = w0[ix]; s0 += a0.x * xj.x + a0.y * xj.y + a0.z * xj.z + a0.w * xj.w;
            const float4 a1 = w1[ix]; s1 += a1.x * xj.x + a1.y * xj.y + a1.z * xj.z + a1.w * xj.w;
            const float4 a2 = w2[ix]; s2 += a2.x * xj.x + a2.y * xj.y + a2.z * xj.z + a2.w * xj.w;
            const float4 a3 = w3[ix]; s3 += a3.x * xj.x + a3.y * xj.y + a3.z * xj.z + a3.w * xj.w;
        }
        #pragma unroll
        for (int off = 32; off > 0; off >>= 1) {
            s0 += __shfl_down(s0, off, 64);
            s1 += __shfl_down(s1, off, 64);
            s2 += __shfl_down(s2, off, 64);
            s3 += __shfl_down(s3, off, 64);
        }
        if (lane == 0) {
            cval[wave][4 * p + 0] = s0; cval[wave][4 * p + 1] = s1;
            cval[wave][4 * p + 2] = s2; cval[wave][4 * p + 3] = s3;
        }
    }

    // ---- rank-based exact top-8 (lanes 0..15) ----
    if (lane < NCAND) {
        const float v = cval[wave][lane];
        const int  ix = cidxs[wave][lane];
        int rank = 0;
        #pragma unroll
        for (int j = 0; j < NCAND; ++j)
            rank += (j != lane) && tk_better(cval[wave][j], cidxs[wave][j], v, ix);
        if (rank < TOPK) { sval[wave][rank] = v; sidx[wave][rank] = ix; }
    }
    if (lane == 0) {
        float s = 0.f;
        #pragma unroll
        for (int k = 0; k < TOPK; ++k) s += fabsf(sval[wave][k]);
        tsum[t] = s;
    }

    // ---- offset: each lane owns 16 output elems (float4 idx lane + 64*j) ----
    float4 a0 = make_float4(0.f, 0.f, 0.f, 0.f), a1 = a0, a2 = a0, a3 = a0;
    #pragma unroll
    for (int k = 0; k < TOPK; ++k) {
        const float s = sval[wave][k];
        const float4* r = (const float4*)(Wdict + (size_t)sidx[wave][k] * D_MODEL);
        const float4 r0 = r[lane], r1 = r[lane + 64], r2 = r[lane + 128], r3 = r[lane + 192];
        a0.x += s * r0.x; a0.y += s * r0.y; a0.z += s * r0.z; a0.w += s * r0.w;
        a1.x += s * r1.x; a1.y += s * r1.y; a1.z += s * r1.z; a1.w += s * r1.w;
        a2.x += s * r2.x; a2.y += s * r2.y; a2.z += s * r2.z; a2.w += s * r2.w;
        a3.x += s * r3.x; a3.y += s * r3.y; a3.z += s * r3.z; a3.w += s * r3.w;
    }
    float4* op = (float4*)(outp + (size_t)t * D_MODEL);
    op[lane] = a0; op[lane + 64] = a1; op[lane + 128] = a2; op[lane + 192] = a3;
}

// ---------------------------------------------------------------------------
// loss = sum(tsum) / (NTOK*DICT)
// ---------------------------------------------------------------------------
__global__ __launch_bounds__(256) void ssod_loss(const float* __restrict__ tsum,
                                                 float* __restrict__ out) {
    float s = 0.f;
    for (int i = threadIdx.x; i < NTOK; i += 256) s += tsum[i];
    #pragma unroll
    for (int off = 32; off > 0; off >>= 1) s += __shfl_down(s, off, 64);
    __shared__ float wsum[4];
    if ((threadIdx.x & 63) == 0) wsum[threadIdx.x >> 6] = s;
    __syncthreads();
    if (threadIdx.x == 0) {
        const float tot = wsum[0] + wsum[1] + wsum[2] + wsum[3];
        out[(size_t)NTOK * D_MODEL] = tot / (float)COEFF_COUNT;
    }
}

// ---------------------------------------------------------------------------
extern "C" void kernel_launch(void* const* d_in, const int* in_sizes, int n_in,
                              void* d_out, int out_size, void* d_ws, size_t ws_size,
                              hipStream_t stream) {
    const float* x     = (const float*)d_in[0];   // [4096,1024]
    const float* Wenc  = (const float*)d_in[1];   // [16384,1024]
    const float* Wdict = (const float*)d_in[2];   // [16384,1024]
    float* out = (float*)d_out;

    char* ws = (char*)d_ws;
    size_t off = 0;
    unsigned short* xbf  = (unsigned short*)(ws + off); off += (size_t)NTOK * D_MODEL * 2;  // 8 MB
    unsigned short* wbf  = (unsigned short*)(ws + off); off += (size_t)DICT * D_MODEL * 2;  // 33.6 MB
    unsigned short* tmax = (unsigned short*)(ws + off); off += (size_t)NTOK * NTILE * 2;    // 1 MB
    float* tsum = (float*)(ws + off);                   off += (size_t)NTOK * 4;            // 16 KB
    unsigned short* coeffs = (unsigned short*)(ws + off);

    // largest token chunk whose bf16 coeff buffer fits remaining ws
    const size_t remain = (ws_size > off) ? (ws_size - off) : 0;
    int chunk = 512;
    if (remain >= (size_t)4096 * DICT * 2) chunk = 4096;
    else if (remain >= (size_t)2048 * DICT * 2) chunk = 2048;
    else if (remain >= (size_t)1024 * DICT * 2) chunk = 1024;

    const int nx4 = NTOK * D_MODEL / 4;
    const int nw4 = DICT * D_MODEL / 4;
    ssod_cvt2<<<(nx4 + nw4 + 255) / 256, 256, 0, stream>>>(
        (const float4*)x, (ushort4*)xbf, nx4, (const float4*)Wenc, (ushort4*)wbf, nw4);

    for (int tokBase = 0; tokBase < NTOK; tokBase += chunk) {
        const int mtiles = chunk / 256;
        ssod_gemm_bf16<<<mtiles * 64, 512, 0, stream>>>(xbf + (size_t)tokBase * D_MODEL, wbf, coeffs,
                                                        tmax + (size_t)tokBase * NTILE);
        ssod_select_refine<<<chunk / 4, 256, 0, stream>>>(coeffs, tmax, x, Wenc, Wdict, out, tsum, tokBase);
    }
    ssod_loss<<<1, 256, 0, stream>>>(tsum, out);
}